// Round 4
// baseline (1763.317 us; speedup 1.0000x reference)
//
#include <hip/hip_runtime.h>
#include <stdint.h>

#define B_ 16
#define A_ 256
#define N_ 64
#define F_ 128
#define G_ 25
#define L_ 3
#define P_ (B_*A_)      // 4096 atoms
#define CUTOFF_ 5.0f
#define OFF0_ 1.2f

// shifted softplus: log(1+e^x) - ln2, stable form
__device__ __forceinline__ float sspf(float x) {
    float t = __expf(-fabsf(x));
    return fmaxf(x, 0.0f) + __logf(1.0f + t) - 0.69314718055994531f;
}

// ---- embedding gather ----
__global__ void k_embed(const float* __restrict__ emb, const int* __restrict__ Z,
                        float* __restrict__ x) {
    int t = blockIdx.x * 256 + threadIdx.x;   // P_*F_ threads
    int p = t >> 7, f = t & 127;
    x[t] = emb[Z[p] * F_ + f];
}

// ---- fp32 GEMM: y[4096,128] = x[4096,128] @ w[128,128] (bias-free) ----
__global__ __launch_bounds__(256) void k_proj(const float* __restrict__ xin,
                                              const float* __restrict__ w,
                                              float* __restrict__ yout) {
    __shared__ float xs[16][128];
    int rb = blockIdx.x * 16;
    int t = threadIdx.x;
#pragma unroll
    for (int i = 0; i < 8; ++i) {
        int idx = i * 256 + t;
        xs[idx >> 7][idx & 127] = xin[rb * 128 + idx];
    }
    __syncthreads();
    int c = t & 127;
    int rg = (t >> 7) * 8;
    float acc[8] = {0, 0, 0, 0, 0, 0, 0, 0};
    for (int k = 0; k < 128; ++k) {
        float wv = w[k * 128 + c];
#pragma unroll
        for (int i = 0; i < 8; ++i) acc[i] += xs[rg + i][k] * wv;
    }
#pragma unroll
    for (int i = 0; i < 8; ++i) yout[(rb + rg + i) * 128 + c] = acc[i];
}

// ---- fused per-atom layer kernel, pure VALU fp32 ----
// WG = 1 atom (256 thr). RBF -> H1=ssp(f@W1+b1) -> W=(H1@W2+b2)*fcut ->
// agg[f] = sum_e W[e][f] * y[nbr(e)][f]
__global__ __launch_bounds__(256) void k_layer(
        const float* __restrict__ pos, const int* __restrict__ nbr,
        const float* __restrict__ mask, const float* __restrict__ y,
        const float* __restrict__ w1, const float* __restrict__ b1,
        const float* __restrict__ w2, const float* __restrict__ b2,
        float* __restrict__ agg)
{
    __shared__ float fij_s[64][33];    // +1 pad: column reads 2-way max
    __shared__ float hw_s[64][129];    // H1, then masked W; +1 pad
    __shared__ float r_s[64];
    __shared__ float fc_s[64];
    __shared__ int   jr_s[64];
    __shared__ float wsum[2][128];
    const int t = threadIdx.x;
    const int atom = blockIdx.x;
    const int molbase = atom & ~(A_ - 1);

    if (t < 64) {
        const int jg = molbase + nbr[atom * N_ + t];
        const float dx = pos[jg * 3 + 0] - pos[atom * 3 + 0];
        const float dy = pos[jg * 3 + 1] - pos[atom * 3 + 1];
        const float dz = pos[jg * 3 + 2] - pos[atom * 3 + 2];
        const float r = sqrtf(dx * dx + dy * dy + dz * dz + 1e-9f);
        r_s[t] = r;
        jr_s[t] = jg;
        fc_s[t] = (r <= CUTOFF_) ? mask[atom * N_ + t] : 0.0f;
    }
    __syncthreads();

    const float step = 3.8f / 24.0f;
    const float coef = -0.5f / (step * step);
#pragma unroll
    for (int i = 0; i < 8; ++i) {                 // 64*32 slots
        const int idx = i * 256 + t;
        const int e = idx >> 5, k = idx & 31;
        float v = 0.0f;
        if (k < G_) { const float d = r_s[e] - (OFF0_ + step * (float)k); v = __expf(coef * d * d); }
        fij_s[e][k] = v;
    }
    __syncthreads();

    const int e  = t & 63;
    const int cb = (t >> 6) * 32;                 // wave q owns cols [q*32, q*32+32)
    float acc[32];
#pragma unroll
    for (int c = 0; c < 32; ++c) acc[c] = b1[cb + c];
    for (int k = 0; k < G_; ++k) {
        const float f = fij_s[e][k];
        const float* wr = w1 + k * F_ + cb;       // wave-uniform row, HW broadcast
#pragma unroll
        for (int c = 0; c < 32; ++c) acc[c] = fmaf(f, wr[c], acc[c]);
    }
#pragma unroll
    for (int c = 0; c < 32; ++c) hw_s[e][cb + c] = sspf(acc[c]);
    __syncthreads();

#pragma unroll
    for (int c = 0; c < 32; ++c) acc[c] = b2[cb + c];
    for (int k = 0; k < F_; ++k) {
        const float h = hw_s[e][k];
        const float* wr = w2 + k * F_ + cb;
#pragma unroll
        for (int c = 0; c < 32; ++c) acc[c] = fmaf(h, wr[c], acc[c]);
    }
    __syncthreads();                               // all H1 reads done
    const float fcv = fc_s[e];
#pragma unroll
    for (int c = 0; c < 32; ++c) hw_s[e][cb + c] = acc[c] * fcv;   // masked W
    __syncthreads();

    // reduce over edges: thread owns col c2, half of edges
    const int c2 = t & 127;
    const int eh = (t >> 7) * 32;
    float s = 0.0f;
    for (int ee = 0; ee < 32; ++ee) {
        const int er = eh + ee;
        s += hw_s[er][c2] * y[(size_t)jr_s[er] * F_ + c2];  // coalesced y row reads
    }
    wsum[t >> 7][c2] = s;
    __syncthreads();
    if (t < F_) agg[(size_t)atom * F_ + t] = wsum[0][t] + wsum[1][t];
}

// ---- atom MLP: x += ssp(agg@wa + ba) @ wb + bb ----
__global__ __launch_bounds__(256) void k_out_mlp(
        const float* __restrict__ agg,
        const float* __restrict__ wa, const float* __restrict__ ba,
        const float* __restrict__ wb, const float* __restrict__ bb,
        float* __restrict__ x)
{
    __shared__ float s0[16][128];
    __shared__ float s1[16][128];
    int rb = blockIdx.x * 16;
    int t = threadIdx.x;
#pragma unroll
    for (int i = 0; i < 8; ++i) {
        int idx = i * 256 + t;
        s0[idx >> 7][idx & 127] = agg[rb * 128 + idx];
    }
    __syncthreads();
    int c = t & 127;
    int rg = (t >> 7) * 8;
    float acc[8] = {0, 0, 0, 0, 0, 0, 0, 0};
    for (int k = 0; k < 128; ++k) {
        float wv = wa[k * 128 + c];
#pragma unroll
        for (int i = 0; i < 8; ++i) acc[i] += s0[rg + i][k] * wv;
    }
    float bva = ba[c];
#pragma unroll
    for (int i = 0; i < 8; ++i) s1[rg + i][c] = sspf(acc[i] + bva);
    __syncthreads();
    float acc2[8] = {0, 0, 0, 0, 0, 0, 0, 0};
    for (int k = 0; k < 128; ++k) {
        float wv = wb[k * 128 + c];
#pragma unroll
        for (int i = 0; i < 8; ++i) acc2[i] += s1[rg + i][k] * wv;
    }
    float bvb = bb[c];
#pragma unroll
    for (int i = 0; i < 8; ++i) x[(rb + rg + i) * 128 + c] += acc2[i] + bvb;
}

// ---- final copy fp32 -> fp32 d_out (reference output dtype is float32) ----
__global__ void k_copy_out(const float* __restrict__ x, float* __restrict__ out) {
    int t = blockIdx.x * 256 + threadIdx.x;
    out[t] = x[t];
}

extern "C" void kernel_launch(void* const* d_in, const int* in_sizes, int n_in,
                              void* d_out, int out_size, void* d_ws, size_t ws_size,
                              hipStream_t stream) {
    const float* emb   = (const float*)d_in[0];
    const float* pos   = (const float*)d_in[1];
    const float* fw1   = (const float*)d_in[2];
    const float* fb1   = (const float*)d_in[3];
    const float* fw2   = (const float*)d_in[4];
    const float* fb2   = (const float*)d_in[5];
    const float* in2f  = (const float*)d_in[6];
    const float* f2o_w = (const float*)d_in[7];
    const float* f2o_b = (const float*)d_in[8];
    const float* dns_w = (const float*)d_in[9];
    const float* dns_b = (const float*)d_in[10];
    const int*   Z     = (const int*)d_in[11];
    const int*   nbrs  = (const int*)d_in[12];
    const float* mask  = (const float*)d_in[13];

    char* ws = (char*)d_ws;
    size_t off = 0;
    auto alloc = [&](size_t bytes) {
        char* p = ws + off; off += (bytes + 255) & ~(size_t)255; return p;
    };
    float* x   = (float*)alloc((size_t)P_ * F_ * 4);
    float* y   = (float*)alloc((size_t)P_ * F_ * 4);
    float* agg = (float*)alloc((size_t)P_ * F_ * 4);
    // total scratch: 6 MB

    k_embed<<<(P_ * F_) / 256, 256, 0, stream>>>(emb, Z, x);

    for (int l = 0; l < L_; ++l) {
        k_proj<<<P_ / 16, 256, 0, stream>>>(x, in2f + (size_t)l * F_ * F_, y);
        k_layer<<<P_, 256, 0, stream>>>(pos, nbrs, mask, y,
                                        fw1 + (size_t)l * G_ * F_, fb1 + (size_t)l * F_,
                                        fw2 + (size_t)l * F_ * F_, fb2 + (size_t)l * F_,
                                        agg);
        k_out_mlp<<<P_ / 16, 256, 0, stream>>>(agg,
                                               f2o_w + (size_t)l * F_ * F_, f2o_b + (size_t)l * F_,
                                               dns_w + (size_t)l * F_ * F_, dns_b + (size_t)l * F_,
                                               x);
    }
    k_copy_out<<<(P_ * F_) / 256, 256, 0, stream>>>(x, (float*)d_out);
}

// Round 5
// 335.675 us; speedup vs baseline: 5.2531x; 5.2531x over previous
//
#include <hip/hip_runtime.h>
#include <stdint.h>

#define B_ 16
#define A_ 256
#define N_ 64
#define F_ 128
#define G_ 25
#define GP 32           // G padded to MFMA K=32
#define L_ 3
#define P_ (B_*A_)      // 4096 atoms
#define CUTOFF_ 5.0f
#define OFF0_ 1.2f

typedef float f32x4 __attribute__((ext_vector_type(4)));
typedef __bf16 bf16x8 __attribute__((ext_vector_type(8)));

__device__ __forceinline__ uint16_t f2bf(float f) {
    union { float f; uint32_t u; } v; v.f = f;
    uint32_t u = v.u;
    return (uint16_t)((u + 0x7FFFu + ((u >> 16) & 1u)) >> 16);  // RNE
}
// shifted softplus: log(1+e^x) - ln2, stable form
__device__ __forceinline__ float sspf(float x) {
    float t = __expf(-fabsf(x));
    return fmaxf(x, 0.0f) + __logf(1.0f + t) - 0.69314718055994531f;
}

// ---- prep: transpose+pad filter weights to bf16 ----
// w1t[l][f][k] (k<32, zero-padded), w2t[l][f][k]
__global__ void k_prepw(const float* __restrict__ fw1, const float* __restrict__ fw2,
                        uint16_t* __restrict__ w1t, uint16_t* __restrict__ w2t) {
    int t = blockIdx.x * 256 + threadIdx.x;
    if (t < L_ * F_ * GP) {
        int k = t & (GP - 1); int f = (t >> 5) & (F_ - 1); int l = t >> 12;
        float v = (k < G_) ? fw1[(l * G_ + k) * F_ + f] : 0.0f;
        w1t[t] = f2bf(v);
    }
    if (t < L_ * F_ * F_) {
        int k = t & (F_ - 1); int f = (t >> 7) & (F_ - 1); int l = t >> 14;
        w2t[t] = f2bf(fw2[(l * F_ + k) * F_ + f]);
    }
}

// ---- embedding gather ----
__global__ void k_embed(const float* __restrict__ emb, const int* __restrict__ Z,
                        float* __restrict__ x) {
    int t = blockIdx.x * 256 + threadIdx.x;   // P_*F_ threads
    int p = t >> 7, f = t & 127;
    x[t] = emb[Z[p] * F_ + f];
}

// ---- fp32 GEMM: y[4096,128] = x[4096,128] @ w[128,128] (bias-free) ----
__global__ __launch_bounds__(256) void k_proj(const float* __restrict__ xin,
                                              const float* __restrict__ w,
                                              float* __restrict__ yout) {
    __shared__ float xs[16][128];
    int rb = blockIdx.x * 16;
    int t = threadIdx.x;
#pragma unroll
    for (int i = 0; i < 8; ++i) {
        int idx = i * 256 + t;
        xs[idx >> 7][idx & 127] = xin[rb * 128 + idx];
    }
    __syncthreads();
    int c = t & 127;
    int rg = (t >> 7) * 8;
    float acc[8] = {0, 0, 0, 0, 0, 0, 0, 0};
    for (int k = 0; k < 128; ++k) {
        float wv = w[k * 128 + c];
#pragma unroll
        for (int i = 0; i < 8; ++i) acc[i] += xs[rg + i][k] * wv;
    }
#pragma unroll
    for (int i = 0; i < 8; ++i) yout[(rb + rg + i) * 128 + c] = acc[i];
}

// ---- fused per-atom layer kernel (MFMA) ----
// WG = 1 atom (256 thr, 4 waves); wave w owns edges [w*16, w*16+16).
// RBF -> H1=ssp(f@W1+b1) -> W=(H1@W2+b2)*fcut -> agg[f]=sum_e W[e][f]*y[nbr(e)][f]
__global__ __launch_bounds__(256) void k_layer(
        const float* __restrict__ pos, const int* __restrict__ nbr,
        const float* __restrict__ mask, const float* __restrict__ y,
        const uint16_t* __restrict__ w1t, const float* __restrict__ b1,
        const uint16_t* __restrict__ w2t, const float* __restrict__ b2,
        float* __restrict__ agg)
{
    __shared__ uint16_t h1[4][16 * 128];   // per-wave swizzled H1 tile (4 KiB each)
    __shared__ float wsum[4][128];
    const int wave = threadIdx.x >> 6;
    const int lane = threadIdx.x & 63;
    const int row  = lane & 15;            // A-row lane index (edge within tile)
    const int kg   = lane >> 4;            // k-group
    const int atom = blockIdx.x;
    const int molbase = atom & ~(A_ - 1);
    const int eg = atom * N_ + wave * 16;

    // --- RBF for this lane's edge (edge = row; duplicated across kg) ---
    const int e_mine = eg + row;
    const int jrow_mine = molbase + nbr[e_mine];
    const float dx = pos[jrow_mine * 3 + 0] - pos[atom * 3 + 0];
    const float dy = pos[jrow_mine * 3 + 1] - pos[atom * 3 + 1];
    const float dz = pos[jrow_mine * 3 + 2] - pos[atom * 3 + 2];
    const float r = sqrtf(dx * dx + dy * dy + dz * dz + 1e-9f);
    const float fcr = (r <= CUTOFF_) ? mask[e_mine] : 0.0f;
    const float step = 3.8f / 24.0f;
    const float coef = -0.5f / (step * step);
    union { bf16x8 v; uint16_t u[8]; } a1;
#pragma unroll
    for (int j = 0; j < 8; ++j) {
        const int k = kg * 8 + j;
        float val = 0.0f;
        if (k < G_) { const float d = r - (OFF0_ + step * (float)k); val = __expf(coef * d * d); }
        a1.u[j] = f2bf(val);
    }

    const f32x4 zero = {0.0f, 0.0f, 0.0f, 0.0f};
    uint16_t* hl = h1[wave];

    // GEMM1: [16,32]@[32,128], ssp epilogue -> XOR-swizzled LDS
#pragma unroll
    for (int nt = 0; nt < 8; ++nt) {
        bf16x8 bfr = *(const bf16x8*)(w1t + (nt * 16 + row) * GP + kg * 8);
        f32x4 acc1 = __builtin_amdgcn_mfma_f32_16x16x32_bf16(a1.v, bfr, zero, 0, 0, 0);
        const int col = nt * 16 + row;
        const float bias = b1[col];
#pragma unroll
        for (int j = 0; j < 4; ++j) {
            const int rr = kg * 4 + j;                         // D-row = edge in tile
            const int byt = rr * 256 + ((col * 2) ^ ((rr & 7) << 4));
            *(uint16_t*)((char*)hl + byt) = f2bf(sspf(acc1[j] + bias));
        }
    }
    __syncthreads();

    // GEMM2: [16,128]@[128,128], K=128 in 4 steps
    f32x4 acc2[8];
#pragma unroll
    for (int nt = 0; nt < 8; ++nt) acc2[nt] = zero;
#pragma unroll
    for (int ks = 0; ks < 4; ++ks) {
        const int kbyte = ks * 64 + kg * 16;
        bf16x8 a2 = *(const bf16x8*)((char*)hl + row * 256 + (kbyte ^ ((row & 7) << 4)));
#pragma unroll
        for (int nt = 0; nt < 8; ++nt) {
            bf16x8 bfr = *(const bf16x8*)(w2t + (nt * 16 + row) * F_ + ks * 32 + kg * 8);
            acc2[nt] = __builtin_amdgcn_mfma_f32_16x16x32_bf16(a2, bfr, acc2[nt], 0, 0, 0);
        }
    }

    // fused epilogue: W = (acc2+b2)*fcut, modulate by gathered y, reduce over edges
    float fc[4]; int jr[4];
#pragma unroll
    for (int j = 0; j < 4; ++j) {
        fc[j] = __shfl(fcr, kg * 4 + j);          // fcut of edge kg*4+j
        jr[j] = __shfl(jrow_mine, kg * 4 + j);    // neighbor row of edge kg*4+j
    }
    float pacc[8];
#pragma unroll
    for (int nt = 0; nt < 8; ++nt) {
        const int col = nt * 16 + row;
        const float b2c = b2[col];
        float s = 0.0f;
#pragma unroll
        for (int j = 0; j < 4; ++j) {
            const float wv = (acc2[nt][j] + b2c) * fc[j];
            s += wv * y[(size_t)jr[j] * F_ + col];
        }
        s += __shfl_xor(s, 16);                   // reduce across kg groups
        s += __shfl_xor(s, 32);
        pacc[nt] = s;
    }
    if (kg == 0) {
#pragma unroll
        for (int nt = 0; nt < 8; ++nt) wsum[wave][nt * 16 + row] = pacc[nt];
    }
    __syncthreads();
    if (threadIdx.x < F_) {
        const int f = threadIdx.x;
        agg[(size_t)atom * F_ + f] = wsum[0][f] + wsum[1][f] + wsum[2][f] + wsum[3][f];
    }
}

// ---- atom MLP: x += ssp(agg@wa + ba) @ wb + bb ----
__global__ __launch_bounds__(256) void k_out_mlp(
        const float* __restrict__ agg,
        const float* __restrict__ wa, const float* __restrict__ ba,
        const float* __restrict__ wb, const float* __restrict__ bb,
        float* __restrict__ x)
{
    __shared__ float s0[16][128];
    __shared__ float s1[16][128];
    int rb = blockIdx.x * 16;
    int t = threadIdx.x;
#pragma unroll
    for (int i = 0; i < 8; ++i) {
        int idx = i * 256 + t;
        s0[idx >> 7][idx & 127] = agg[rb * 128 + idx];
    }
    __syncthreads();
    int c = t & 127;
    int rg = (t >> 7) * 8;
    float acc[8] = {0, 0, 0, 0, 0, 0, 0, 0};
    for (int k = 0; k < 128; ++k) {
        float wv = wa[k * 128 + c];
#pragma unroll
        for (int i = 0; i < 8; ++i) acc[i] += s0[rg + i][k] * wv;
    }
    float bva = ba[c];
#pragma unroll
    for (int i = 0; i < 8; ++i) s1[rg + i][c] = sspf(acc[i] + bva);
    __syncthreads();
    float acc2[8] = {0, 0, 0, 0, 0, 0, 0, 0};
    for (int k = 0; k < 128; ++k) {
        float wv = wb[k * 128 + c];
#pragma unroll
        for (int i = 0; i < 8; ++i) acc2[i] += s1[rg + i][k] * wv;
    }
    float bvb = bb[c];
#pragma unroll
    for (int i = 0; i < 8; ++i) x[(rb + rg + i) * 128 + c] += acc2[i] + bvb;
}

// ---- final copy fp32 -> fp32 d_out (reference output dtype is float32) ----
__global__ void k_copy_out(const float* __restrict__ x, float* __restrict__ out) {
    int t = blockIdx.x * 256 + threadIdx.x;
    out[t] = x[t];
}

extern "C" void kernel_launch(void* const* d_in, const int* in_sizes, int n_in,
                              void* d_out, int out_size, void* d_ws, size_t ws_size,
                              hipStream_t stream) {
    const float* emb   = (const float*)d_in[0];
    const float* pos   = (const float*)d_in[1];
    const float* fw1   = (const float*)d_in[2];
    const float* fb1   = (const float*)d_in[3];
    const float* fw2   = (const float*)d_in[4];
    const float* fb2   = (const float*)d_in[5];
    const float* in2f  = (const float*)d_in[6];
    const float* f2o_w = (const float*)d_in[7];
    const float* f2o_b = (const float*)d_in[8];
    const float* dns_w = (const float*)d_in[9];
    const float* dns_b = (const float*)d_in[10];
    const int*   Z     = (const int*)d_in[11];
    const int*   nbrs  = (const int*)d_in[12];
    const float* mask  = (const float*)d_in[13];

    char* ws = (char*)d_ws;
    size_t off = 0;
    auto alloc = [&](size_t bytes) {
        char* p = ws + off; off += (bytes + 255) & ~(size_t)255; return p;
    };
    float*    x   = (float*)   alloc((size_t)P_ * F_ * 4);
    float*    y   = (float*)   alloc((size_t)P_ * F_ * 4);
    float*    agg = (float*)   alloc((size_t)P_ * F_ * 4);
    uint16_t* w1t = (uint16_t*)alloc((size_t)L_ * F_ * GP * 2);
    uint16_t* w2t = (uint16_t*)alloc((size_t)L_ * F_ * F_ * 2);
    // total scratch: ~6.4 MB

    k_prepw<<<192, 256, 0, stream>>>(fw1, fw2, w1t, w2t);
    k_embed<<<(P_ * F_) / 256, 256, 0, stream>>>(emb, Z, x);

    for (int l = 0; l < L_; ++l) {
        k_proj<<<P_ / 16, 256, 0, stream>>>(x, in2f + (size_t)l * F_ * F_, y);
        k_layer<<<P_, 256, 0, stream>>>(pos, nbrs, mask, y,
                                        w1t + (size_t)l * F_ * GP, fb1 + (size_t)l * F_,
                                        w2t + (size_t)l * F_ * F_, fb2 + (size_t)l * F_,
                                        agg);
        k_out_mlp<<<P_ / 16, 256, 0, stream>>>(agg,
                                               f2o_w + (size_t)l * F_ * F_, f2o_b + (size_t)l * F_,
                                               dns_w + (size_t)l * F_ * F_, dns_b + (size_t)l * F_,
                                               x);
    }
    k_copy_out<<<(P_ * F_) / 256, 256, 0, stream>>>(x, (float*)d_out);
}